// Round 1
// baseline (268.708 us; speedup 1.0000x reference)
//
#include <hip/hip_runtime.h>

#define NAGENTS 8
#define MITEMS 16
#define NM 128          // NAGENTS*MITEMS
#define MENU 256
#define SFULL 257       // MENU + null entry

__device__ __forceinline__ float wredmax(float v) {
#pragma unroll
    for (int o = 32; o; o >>= 1) v = fmaxf(v, __shfl_xor(v, o));
    return v;
}
__device__ __forceinline__ float wredsum(float v) {
#pragma unroll
    for (int o = 32; o; o >>= 1) v += __shfl_xor(v, o);
    return v;
}

__global__ __launch_bounds__(1024) void cama_kernel(
    const float* __restrict__ bids,   // B,8,16
    const float* __restrict__ allocs, // B,256,8,16
    const float* __restrict__ wvec,   // B,8
    const float* __restrict__ bvec,   // B,256
    const float* __restrict__ tempp,  // 1
    float* __restrict__ out, int Bsz)
{
    // LDS: swizzled allocs row (128KB) + per-agent welfare + small scratch
    __shared__ float4 lda4[MENU * 32];            // 131072 B
    __shared__ float lds_pwT[NAGENTS * MENU];     // pw transposed [n][s]
    __shared__ float lds_tot[MENU];
    __shared__ float lds_bb[MENU];
    __shared__ __align__(16) float lds_bids[NM];
    __shared__ float lds_w[NAGENTS];
    __shared__ float lds_ch[SFULL];
    __shared__ float lds_rcs[NAGENTS], lds_rb[NAGENTS], lds_cw[NAGENTS];
    __shared__ float lds_ab;

    const int u = threadIdx.x;
    const int lane = u & 63;
    const int wave = u >> 6;
    const int b = blockIdx.x;
    const size_t bb = (size_t)b;

    float* out_choice = out;                                  // B*257
    float* out_item   = out + (size_t)Bsz * SFULL;            // B*128
    float* out_pay    = out_item + (size_t)Bsz * NM;          // 8*B
    float* out_all    = out_pay + (size_t)NAGENTS * Bsz;      // B*257*128

    // stage small inputs
    if (u < NM) lds_bids[u] = bids[bb * NM + u];
    else if (u < NM + NAGENTS) lds_w[u - NM] = wvec[bb * NAGENTS + (u - NM)];
    if (u >= 256 && u < 512) lds_bb[u - 256] = bvec[bb * MENU + (u - 256)];
    __syncthreads();

    const float temp = tempp[0];
    const int n = u & 7;                 // agent handled by this thread (fixed)
    const float w_n = lds_w[n];
    const float4* bq = (const float4*)lds_bids + (n << 2);
    const float4 q0 = bq[0], q1 = bq[1], q2 = bq[2], q3 = bq[3];

    // Phase 1: stream allocs[b]: global->reg, reg->out copy, reg->LDS (swizzled),
    // compute per-(s,n) welfare in-register.
#pragma unroll
    for (int i = 0; i < 2; ++i) {
        const int s = (i << 7) + (u >> 3);
        const float4* src = (const float4*)(allocs + ((bb << 8) + s) * NM) + (n << 2);
        float4 a0 = src[0], a1 = src[1], a2 = src[2], a3 = src[3];
        float4* dst = (float4*)(out_all + (bb * SFULL + s) * NM) + (n << 2);
        dst[0] = a0; dst[1] = a1; dst[2] = a2; dst[3] = a3;
        float util = a0.x*q0.x + a0.y*q0.y + a0.z*q0.z + a0.w*q0.w
                   + a1.x*q1.x + a1.y*q1.y + a1.z*q1.z + a1.w*q1.w
                   + a2.x*q2.x + a2.y*q2.y + a2.z*q2.z + a2.w*q2.w
                   + a3.x*q3.x + a3.y*q3.y + a3.z*q3.z + a3.w*q3.w;
        float pwv = w_n * util;
        lds_pwT[(n << 8) + s] = pwv;
        float t4 = pwv;
        t4 += __shfl_xor(t4, 1);
        t4 += __shfl_xor(t4, 2);
        t4 += __shfl_xor(t4, 4);
        if (n == 0) lds_tot[s] = t4;
        const int base = s << 5, c7 = s & 7, j0 = n << 2;
        lda4[base + ((j0 + 0) ^ c7)] = a0;
        lda4[base + ((j0 + 1) ^ c7)] = a1;
        lda4[base + ((j0 + 2) ^ c7)] = a2;
        lda4[base + ((j0 + 3) ^ c7)] = a3;
    }
    // null menu entry in output allocs = zeros
    if (u < 32) {
        float4 z = make_float4(0.f, 0.f, 0.f, 0.f);
        ((float4*)(out_all + (bb * SFULL + MENU) * NM))[u] = z;
    }
    __syncthreads();

    // Round A: 9 softmaxes, one per wave (wave0 = full, waves 1..8 = leave-one-out)
    if (wave == 0) {
        float xs[4], bl[4], es[4];
        float mx = -1e30f;
#pragma unroll
        for (int c = 0; c < 4; ++c) {
            int v = (c << 6) | lane;
            bl[c] = lds_bb[v];
            float x = (lds_tot[v] + bl[c]) * temp;
            xs[c] = x; mx = fmaxf(mx, x);
        }
        mx = fmaxf(wredmax(mx), 0.f);   // null entry has x=0
        float se = 0.f, sab = 0.f;
#pragma unroll
        for (int c = 0; c < 4; ++c) { es[c] = __expf(xs[c] - mx); se += es[c]; sab += es[c] * bl[c]; }
        float en = __expf(-mx);
        se = wredsum(se) + en;
        sab = wredsum(sab);             // null adds b=0
        float inv = 1.f / se;
#pragma unroll
        for (int c = 0; c < 4; ++c) {
            int v = (c << 6) | lane;
            float chv = es[c] * inv;
            lds_ch[v] = chv;
            out_choice[bb * SFULL + v] = chv;
        }
        if (lane == 0) {
            float chn = en * inv;
            lds_ch[MENU] = chn;
            out_choice[bb * SFULL + MENU] = chn;
            lds_ab = sab * inv;
        }
    } else if (wave <= 8) {
        const int i = wave - 1;
        float xs[4], trs[4], bl[4];
        float mx = -1e30f;
#pragma unroll
        for (int c = 0; c < 4; ++c) {
            int v = (c << 6) | lane;
            bl[c] = lds_bb[v];
            float tr = lds_tot[v] - lds_pwT[(i << 8) + v];  // total minus agent i
            trs[c] = tr;
            float x = (tr + bl[c]) * temp;
            xs[c] = x; mx = fmaxf(mx, x);
        }
        mx = fmaxf(wredmax(mx), 0.f);
        float se = 0.f, s1 = 0.f, s2 = 0.f;
#pragma unroll
        for (int c = 0; c < 4; ++c) {
            float e = __expf(xs[c] - mx);
            se += e; s1 += e * trs[c]; s2 += e * bl[c];
        }
        se = wredsum(se) + __expf(-mx);
        s1 = wredsum(s1);
        s2 = wredsum(s2);
        if (lane == 0) { lds_rcs[i] = s1 / se; lds_rb[i] = s2 / se; }
    }
    __syncthreads();

    // Round B: chosen welfare per agent (waves 0-7), then item_allocation (all waves)
    if (wave < 8) {
        float cwv = 0.f;
#pragma unroll
        for (int c = 0; c < 4; ++c) {
            int v = (c << 6) | lane;
            cwv += lds_ch[v] * lds_pwT[(wave << 8) + v];
        }
        cwv = wredsum(cwv);
        if (lane == 0) lds_cw[wave] = cwv;
    }
    {
        const float* ldf = (const float*)lda4;
        const int wl = lane & 7, chunk = lane >> 3;
        const int nm = (wave << 3) + wl;       // word this lane-group accumulates
        const int jj = nm >> 2, r = nm & 3;
        float acc = 0.f;
#pragma unroll 4
        for (int it = 0; it < 32; ++it) {
            int s = (it << 3) + chunk;
            float av = ldf[(((s << 5) + (jj ^ (s & 7))) << 2) + r];
            acc += lds_ch[s] * av;
        }
        acc += __shfl_xor(acc, 8);
        acc += __shfl_xor(acc, 16);
        acc += __shfl_xor(acc, 32);
        if (chunk == 0) out_item[bb * NM + nm] = acc;
    }
    __syncthreads();

    // payments: (rcs + rb - (chosen_tot - cw[i]) - ab) / w[b,i], layout (n,B)
    if (u < NAGENTS) {
        float ctot = 0.f;
#pragma unroll
        for (int k = 0; k < NAGENTS; ++k) ctot += lds_cw[k];
        float pay = (lds_rcs[u] + lds_rb[u] - (ctot - lds_cw[u]) - lds_ab) / lds_w[u];
        out_pay[(size_t)u * Bsz + b] = pay;
    }
}

extern "C" void kernel_launch(void* const* d_in, const int* in_sizes, int n_in,
                              void* d_out, int out_size, void* d_ws, size_t ws_size,
                              hipStream_t stream) {
    const float* bids   = (const float*)d_in[0];
    const float* allocs = (const float*)d_in[1];
    const float* wvec   = (const float*)d_in[2];
    const float* bvec   = (const float*)d_in[3];
    const float* tempp  = (const float*)d_in[4];
    float* out = (float*)d_out;
    const int Bsz = in_sizes[0] / (NAGENTS * MITEMS);  // 4096
    cama_kernel<<<Bsz, 1024, 0, stream>>>(bids, allocs, wvec, bvec, tempp, out, Bsz);
}

// Round 2
// 255.413 us; speedup vs baseline: 1.0521x; 1.0521x over previous
//
#include <hip/hip_runtime.h>

#define NAGENTS 8
#define MITEMS 16
#define NM 128          // NAGENTS*MITEMS
#define MENU 256
#define SFULL 257       // MENU + null entry

__device__ __forceinline__ float wredmax(float v) {
#pragma unroll
    for (int o = 32; o; o >>= 1) v = fmaxf(v, __shfl_xor(v, o));
    return v;
}
__device__ __forceinline__ float wredsum(float v) {
#pragma unroll
    for (int o = 32; o; o >>= 1) v += __shfl_xor(v, o);
    return v;
}

// 512 threads/block, one block per auction b. Payload split: menu rows 0..127
// in registers (32 floats/thread), rows 128..255 in swizzled LDS (64KB).
// LDS total ~75.7KB -> 2 blocks/CU resident: one block streams HBM while the
// other runs its softmax/item phases.
__global__ __launch_bounds__(512, 4) void cama_kernel(
    const float* __restrict__ bids,   // B,8,16
    const float* __restrict__ allocs, // B,256,8,16
    const float* __restrict__ wvec,   // B,8
    const float* __restrict__ bvec,   // B,256
    const float* __restrict__ tempp,  // 1
    float* __restrict__ out, int Bsz)
{
    __shared__ float4 lda4[128 * 32];             // 64KB: rows s=128..255, swizzled
    __shared__ float lds_pwT[NAGENTS * MENU];     // 8KB: pw [n][s^swz]; later overlaid by item scratch
    __shared__ float lds_tot[MENU];
    __shared__ float lds_bb[MENU];
    __shared__ __align__(16) float lds_bids[NM];
    __shared__ float lds_w[NAGENTS];
    __shared__ float lds_ch[SFULL];
    __shared__ float lds_rcs[NAGENTS], lds_rb[NAGENTS], lds_cw[NAGENTS];
    __shared__ float lds_ab;

    const int u = threadIdx.x;       // 0..511
    const int lane = u & 63;
    const int wave = u >> 6;         // 0..7
    const int n = u & 7;             // agent slice owned by this thread
    const int sg = u >> 3;           // 0..63 (s-group)
    const int b = blockIdx.x;
    const size_t bb = (size_t)b;

    float* out_choice = out;                                  // B*257
    float* out_item   = out + (size_t)Bsz * SFULL;            // B*128
    float* out_pay    = out_item + (size_t)Bsz * NM;          // 8*B
    float* out_all    = out_pay + (size_t)NAGENTS * Bsz;      // B*257*128

    // stage small inputs
    if (u < NM) lds_bids[u] = bids[bb * NM + u];
    if (u >= NM && u < NM + NAGENTS) lds_w[u - NM] = wvec[bb * NAGENTS + (u - NM)];
    if (u >= 256) lds_bb[u - 256] = bvec[bb * MENU + (u - 256)];
    __syncthreads();

    const float temp = tempp[0];
    const float w_n = lds_w[n];
    const float4* bq = (const float4*)lds_bids + (n << 2);
    const float4 q0 = bq[0], q1 = bq[1], q2 = bq[2], q3 = bq[3];

    float4 P00, P01, P02, P03, P10, P11, P12, P13;  // payload rows s=sg and s=64+sg

    // Phase 1: stream allocs[b]: global->reg, reg->out copy, welfare, payload keep
#pragma unroll
    for (int c = 0; c < 4; ++c) {
        const int s = (c << 6) + sg;
        const float4* src = (const float4*)(allocs + ((bb << 8) + s) * NM) + (n << 2);
        float4 a0 = src[0], a1 = src[1], a2 = src[2], a3 = src[3];
        float4* dst = (float4*)(out_all + (bb * SFULL + s) * NM) + (n << 2);
        dst[0] = a0; dst[1] = a1; dst[2] = a2; dst[3] = a3;
        float util = a0.x*q0.x + a0.y*q0.y + a0.z*q0.z + a0.w*q0.w
                   + a1.x*q1.x + a1.y*q1.y + a1.z*q1.z + a1.w*q1.w
                   + a2.x*q2.x + a2.y*q2.y + a2.z*q2.z + a2.w*q2.w
                   + a3.x*q3.x + a3.y*q3.y + a3.z*q3.z + a3.w*q3.w;
        float pwv = w_n * util;
        lds_pwT[(n << 8) + (s ^ (n << 2))] = pwv;   // swizzled: conflict-free write & read
        float t4 = pwv;
        t4 += __shfl_xor(t4, 1);
        t4 += __shfl_xor(t4, 2);
        t4 += __shfl_xor(t4, 4);
        if (n == 0) lds_tot[s] = t4;
        if (c == 0)      { P00 = a0; P01 = a1; P02 = a2; P03 = a3; }
        else if (c == 1) { P10 = a0; P11 = a1; P12 = a2; P13 = a3; }
        else {
            const int base = (s - 128) << 5, c7 = s & 7, j0 = n << 2;
            lda4[base + ((j0 + 0) ^ c7)] = a0;
            lda4[base + ((j0 + 1) ^ c7)] = a1;
            lda4[base + ((j0 + 2) ^ c7)] = a2;
            lda4[base + ((j0 + 3) ^ c7)] = a3;
        }
    }
    // null menu entry in output allocs = zeros
    if (u < 32) {
        float4 z = make_float4(0.f, 0.f, 0.f, 0.f);
        ((float4*)(out_all + (bb * SFULL + MENU) * NM))[u] = z;
    }
    __syncthreads();

    // Round A: full softmax (wave 0) + 8 leave-one-out softmaxes (wave i -> agent i)
    if (wave == 0) {
        float xs[4], bl[4], es[4];
        float mx = -1e30f;
#pragma unroll
        for (int c = 0; c < 4; ++c) {
            int v = (c << 6) | lane;
            bl[c] = lds_bb[v];
            float x = (lds_tot[v] + bl[c]) * temp;
            xs[c] = x; mx = fmaxf(mx, x);
        }
        mx = fmaxf(wredmax(mx), 0.f);   // null entry has x=0
        float se = 0.f, sab = 0.f;
#pragma unroll
        for (int c = 0; c < 4; ++c) { es[c] = __expf(xs[c] - mx); se += es[c]; sab += es[c] * bl[c]; }
        float en = __expf(-mx);
        se = wredsum(se) + en;
        sab = wredsum(sab);
        float inv = 1.f / se;
#pragma unroll
        for (int c = 0; c < 4; ++c) {
            int v = (c << 6) | lane;
            float chv = es[c] * inv;
            lds_ch[v] = chv;
            out_choice[bb * SFULL + v] = chv;
        }
        if (lane == 0) {
            float chn = en * inv;
            lds_ch[MENU] = chn;
            out_choice[bb * SFULL + MENU] = chn;
            lds_ab = sab * inv;
        }
    }
    {
        const int i = wave;
        float xs[4], trs[4], bl[4];
        float mx = -1e30f;
#pragma unroll
        for (int c = 0; c < 4; ++c) {
            int v = (c << 6) | lane;
            bl[c] = lds_bb[v];
            float tr = lds_tot[v] - lds_pwT[(i << 8) + (v ^ (i << 2))];
            trs[c] = tr;
            float x = (tr + bl[c]) * temp;
            xs[c] = x; mx = fmaxf(mx, x);
        }
        mx = fmaxf(wredmax(mx), 0.f);
        float se = 0.f, s1 = 0.f, s2 = 0.f;
#pragma unroll
        for (int c = 0; c < 4; ++c) {
            float e = __expf(xs[c] - mx);
            se += e; s1 += e * trs[c]; s2 += e * bl[c];
        }
        se = wredsum(se) + __expf(-mx);
        s1 = wredsum(s1);
        s2 = wredsum(s2);
        if (lane == 0) { lds_rcs[i] = s1 / se; lds_rb[i] = s2 / se; }
    }
    __syncthreads();

    // Round B1: chosen welfare per agent (wave i -> agent i); last use of pwT
    {
        const int i = wave;
        float cwv = 0.f;
#pragma unroll
        for (int c = 0; c < 4; ++c) {
            int v = (c << 6) | lane;
            cwv += lds_ch[v] * lds_pwT[(i << 8) + (v ^ (i << 2))];
        }
        cwv = wredsum(cwv);
        if (lane == 0) lds_cw[i] = cwv;
    }
    __syncthreads();   // pwT reads done -> scratch overlay safe

    // Item allocation: reg part (s 0..127) + LDS part (s 128..255)
    float* scratchA = lds_pwT;          // 8 waves x 128 words (4KB)
    float* scratchB = lds_pwT + 1024;   // 4 groups x 128 words (2KB)
    {
        float c0 = lds_ch[sg], c1 = lds_ch[64 + sg];
        float vs[16];
        vs[ 0] = P00.x*c0 + P10.x*c1;  vs[ 1] = P00.y*c0 + P10.y*c1;
        vs[ 2] = P00.z*c0 + P10.z*c1;  vs[ 3] = P00.w*c0 + P10.w*c1;
        vs[ 4] = P01.x*c0 + P11.x*c1;  vs[ 5] = P01.y*c0 + P11.y*c1;
        vs[ 6] = P01.z*c0 + P11.z*c1;  vs[ 7] = P01.w*c0 + P11.w*c1;
        vs[ 8] = P02.x*c0 + P12.x*c1;  vs[ 9] = P02.y*c0 + P12.y*c1;
        vs[10] = P02.z*c0 + P12.z*c1;  vs[11] = P02.w*c0 + P12.w*c1;
        vs[12] = P03.x*c0 + P13.x*c1;  vs[13] = P03.y*c0 + P13.y*c1;
        vs[14] = P03.z*c0 + P13.z*c1;  vs[15] = P03.w*c0 + P13.w*c1;
#pragma unroll
        for (int wd = 0; wd < 16; ++wd) {
            float t = vs[wd];
            t += __shfl_xor(t, 8);
            t += __shfl_xor(t, 16);
            t += __shfl_xor(t, 32);
            vs[wd] = t;
        }
        if (lane < 8) {   // lane == n: holds the reduced n-slice for this wave's 16 s-rows
            float4* d4 = (float4*)(scratchA + (wave << 7) + (lane << 4));
            d4[0] = make_float4(vs[ 0], vs[ 1], vs[ 2], vs[ 3]);
            d4[1] = make_float4(vs[ 4], vs[ 5], vs[ 6], vs[ 7]);
            d4[2] = make_float4(vs[ 8], vs[ 9], vs[10], vs[11]);
            d4[3] = make_float4(vs[12], vs[13], vs[14], vs[15]);
        }
    }
    {
        const int nm = u & 127, k = u >> 7;   // 4 groups of 32 s-rows each
        const int jj = nm >> 2, r = nm & 3;
        const float* ldf = (const float*)lda4;
        float acc = 0.f;
#pragma unroll 8
        for (int it = 0; it < 32; ++it) {
            int sl = (k << 5) + it;           // s = 128 + sl
            acc += lds_ch[128 + sl] * ldf[(sl << 7) + (((jj ^ (sl & 7)) << 2) | r)];
        }
        scratchB[(k << 7) + nm] = acc;
    }
    __syncthreads();

    if (u < NM) {
        float sum = 0.f;
#pragma unroll
        for (int w = 0; w < 8; ++w) sum += scratchA[(w << 7) + u];
#pragma unroll
        for (int k = 0; k < 4; ++k) sum += scratchB[(k << 7) + u];
        out_item[bb * NM + u] = sum;
    }
    // payments: (rcs + rb - (chosen_tot - cw[i]) - ab) / w[b,i], layout (n,B)
    if (u < NAGENTS) {
        float ctot = 0.f;
#pragma unroll
        for (int k = 0; k < NAGENTS; ++k) ctot += lds_cw[k];
        float pay = (lds_rcs[u] + lds_rb[u] - (ctot - lds_cw[u]) - lds_ab) / lds_w[u];
        out_pay[(size_t)u * Bsz + b] = pay;
    }
}

extern "C" void kernel_launch(void* const* d_in, const int* in_sizes, int n_in,
                              void* d_out, int out_size, void* d_ws, size_t ws_size,
                              hipStream_t stream) {
    const float* bids   = (const float*)d_in[0];
    const float* allocs = (const float*)d_in[1];
    const float* wvec   = (const float*)d_in[2];
    const float* bvec   = (const float*)d_in[3];
    const float* tempp  = (const float*)d_in[4];
    float* out = (float*)d_out;
    const int Bsz = in_sizes[0] / (NAGENTS * MITEMS);  // 4096
    cama_kernel<<<Bsz, 512, 0, stream>>>(bids, allocs, wvec, bvec, tempp, out, Bsz);
}